// Round 13
// baseline (3765.458 us; speedup 1.0000x reference)
//
#include <hip/hip_runtime.h>
#include <hip/hip_bf16.h>

typedef short s16x8 __attribute__((ext_vector_type(8)));
typedef float f32x4 __attribute__((ext_vector_type(4)));

__device__ __forceinline__ float bf2f(unsigned short s) {
  union { unsigned int u; float f; } c; c.u = ((unsigned int)s) << 16; return c.f;
}
__device__ __forceinline__ short f2bf(float f) {
  union { float f; unsigned int u; } c; c.f = f;
  unsigned int r = (c.u + 0x7fffu + ((c.u >> 16) & 1u)) >> 16;
  return (short)(unsigned short)r;
}
__device__ __forceinline__ float sigm(float x) { return 1.0f / (1.0f + __expf(-x)); }

__device__ __forceinline__ void gload_lds16(const short* g, short* l) {
  __builtin_amdgcn_global_load_lds((const __attribute__((address_space(1))) void*)g,
                                   (__attribute__((address_space(3))) void*)l, 16, 0, 0);
}

#define SB() __builtin_amdgcn_sched_barrier(0)
#define WAITV(N) asm volatile("s_waitcnt vmcnt(" #N ")" ::: "memory"); SB();

// batched coherent loads: 8x global_load_dwordx4 sc1 = AGENT scope
// (device coherent point, LLC-cacheable). Previous rounds used sc0 sc1 =
// SYSTEM scope — suspected latency inflator. This is the round's experiment.
__device__ __forceinline__ void cload8(const short* p,
    s16x8& d0, s16x8& d1, s16x8& d2, s16x8& d3,
    s16x8& d4, s16x8& d5, s16x8& d6, s16x8& d7)
{
  asm volatile(
    "global_load_dwordx4 %0, %[p], off sc1\n\t"
    "global_load_dwordx4 %1, %[p], off offset:64 sc1\n\t"
    "global_load_dwordx4 %2, %[p], off offset:128 sc1\n\t"
    "global_load_dwordx4 %3, %[p], off offset:192 sc1\n\t"
    "global_load_dwordx4 %4, %[p], off offset:256 sc1\n\t"
    "global_load_dwordx4 %5, %[p], off offset:320 sc1\n\t"
    "global_load_dwordx4 %6, %[p], off offset:384 sc1\n\t"
    "global_load_dwordx4 %7, %[p], off offset:448 sc1"
    : "=&v"(d0), "=&v"(d1), "=&v"(d2), "=&v"(d3),
      "=&v"(d4), "=&v"(d5), "=&v"(d6), "=&v"(d7)
    : [p]"v"(p) : "memory");
}

// ---------------- prep ----------------
__global__ void prep(const float* __restrict__ x,
                     const float* __restrict__ Wfz, const float* __restrict__ Wfr, const float* __restrict__ Wfh,
                     const float* __restrict__ Wuz, const float* __restrict__ Wur, const float* __restrict__ Wuh,
                     const float* __restrict__ h0,
                     short* __restrict__ xb, short* __restrict__ Wf, short* __restrict__ Wzr,
                     short* __restrict__ Wh, short* __restrict__ hb)
{
  const long NX = 33554432L;
  const long NW = 1048576L;
  const long TOT = NX + 6*NW + 65536L;
  long stride = (long)gridDim.x * blockDim.x;
  for (long p = (long)blockIdx.x * blockDim.x + threadIdx.x; p < TOT; p += stride) {
    if (p < NX) { xb[p] = f2bf(x[p]); }
    else if (p < NX + 3*NW) {
      long q = p - NX;
      float v = q < NW ? Wfz[q] : (q < 2*NW ? Wfr[q-NW] : Wfh[q-2*NW]);
      Wf[q] = f2bf(v);
    } else if (p < NX + 5*NW) {
      long q = p - NX - 3*NW;
      float v = q < NW ? Wuz[q] : Wur[q-NW];
      Wzr[q] = f2bf(v);
    } else if (p < NX + 6*NW) {
      long q = p - NX - 5*NW;
      Wh[q] = f2bf(Wuh[q]);
    } else {
      long q = p - NX - 6*NW;
      hb[q] = f2bf(h0[q]);
    }
  }
}

// ---------------- input GEMM ----------------
__global__ __launch_bounds__(256) void gemm_x(const short* __restrict__ A, const short* __restrict__ Bw,
    const float* __restrict__ bfz, const float* __restrict__ bfr, const float* __restrict__ bfh,
    short* __restrict__ X)
{
  constexpr int M = 32768, K = 1024;
  constexpr int BM = 128, BN = 128, BK = 32;
  __shared__ __align__(16) short As[BM*BK];
  __shared__ __align__(16) short Bs[BN*BK];
  int tid = threadIdx.x, lane = tid & 63, wid = tid >> 6;
  int bm = blockIdx.x % (M/BM), bn = blockIdx.x / (M/BM);
  int wm = wid >> 1, wn = wid & 1;

  f32x4 acc[4][4];
  for (int i = 0; i < 4; ++i) for (int j = 0; j < 4; ++j) acc[i][j] = f32x4{0.f,0.f,0.f,0.f};

  int r0 = tid >> 2,        kc0 = (tid & 3) * 8;
  int r1 = (256+tid) >> 2,  kc1 = ((256+tid) & 3) * 8;
  const short* a0 = A  + (size_t)(bm*BM + r0)*K + kc0;
  const short* a1 = A  + (size_t)(bm*BM + r1)*K + kc1;
  const short* b0 = Bw + (size_t)(bn*BN + r0)*K + kc0;
  const short* b1 = Bw + (size_t)(bn*BN + r1)*K + kc1;

  const short* abase = As + (wm*64 + (lane&15))*BK + (lane>>4)*8;
  const short* bbase = Bs + (wn*64 + (lane&15))*BK + (lane>>4)*8;

  for (int k0 = 0; k0 < K; k0 += BK) {
    __syncthreads();
    gload_lds16(a0 + k0, As + wid*512);
    gload_lds16(a1 + k0, As + 2048 + wid*512);
    gload_lds16(b0 + k0, Bs + wid*512);
    gload_lds16(b1 + k0, Bs + 2048 + wid*512);
    __syncthreads();
    s16x8 af[4], bff[4];
    for (int f = 0; f < 4; ++f) {
      af[f]  = *(const s16x8*)(abase + f*16*BK);
      bff[f] = *(const s16x8*)(bbase + f*16*BK);
    }
    for (int i = 0; i < 4; ++i)
      for (int j = 0; j < 4; ++j)
        acc[i][j] = __builtin_amdgcn_mfma_f32_16x16x32_bf16(af[i], bff[j], acc[i][j], 0, 0, 0);
  }

  int col = lane & 15, rb = (lane >> 4) * 4;
  for (int fi = 0; fi < 4; ++fi) for (int fj = 0; fj < 4; ++fj) {
    int n = bn*BN + wn*64 + fj*16 + col;
    float bias = n < 1024 ? bfz[n] : (n < 2048 ? bfr[n-1024] : bfh[n-2048]);
    f32x4 c = acc[fi][fj];
    for (int i = 0; i < 4; ++i) {
      int m = bm*BM + wm*64 + fi*16 + rb + i;
      int bb = m >> 9, tt = m & 511;
      X[((size_t)tt*64 + bb)*3072 + n] = f2bf(c[i] + bias);
    }
  }
}

#define MFMA(a,b,c) __builtin_amdgcn_mfma_f32_16x16x32_bf16(a,b,c,0,0,0)

// ---------------- persistent recurrence: 256 wgs x 64 thr (round-5 structure,
// agent-scope loads) ----------------
__global__ __launch_bounds__(64, 1) void recur(
  const short* __restrict__ X,    // [512][64][3072] bf16
  const short* __restrict__ Wzr,  // [2048][1024] bf16
  const short* __restrict__ Wh,   // [1024][1024] bf16
  const float* __restrict__ h0,
  const float* __restrict__ buz, const float* __restrict__ bur, const float* __restrict__ buh,
  short* hb,                      // [2][64][1024] bf16 h
  short* rh,                      // [64][1024] bf16 r*h
  float* y, float* hlast, int* bar)
{
  __shared__ __align__(16) short Wl[3*32*64*8];   // 98304 B -> 1 wg per CU

  int wg = blockIdx.x;
  int cg = wg & 63, bg = wg >> 6;
  int lane = threadIdx.x;
  int col = lane & 15, hi = lane >> 4;
  int rb = hi*4, kfo = hi*8;
  int j  = cg*16 + col;
  int b0 = bg*16 + rb;
  int arow = bg*16 + col;

  // stage weights to LDS, fragment-ordered
  {
    const short* gbase0 = Wzr + (size_t)(cg*16 + col)*1024 + kfo;
    const short* gbase1 = Wzr + (size_t)(1024 + cg*16 + col)*1024 + kfo;
    const short* gbase2 = Wh  + (size_t)(cg*16 + col)*1024 + kfo;
    #pragma unroll 4
    for (int n = 0; n < 32; ++n) {
      *(s16x8*)(Wl + ((0*32+n)*64 + lane)*8) = *(const s16x8*)(gbase0 + n*32);
      *(s16x8*)(Wl + ((1*32+n)*64 + lane)*8) = *(const s16x8*)(gbase1 + n*32);
      *(s16x8*)(Wl + ((2*32+n)*64 + lane)*8) = *(const s16x8*)(gbase2 + n*32);
    }
  }

  float bz = buz[j], br = bur[j], bh = buh[j];
  float hreg[4], zreg[4];
  #pragma unroll
  for (int i = 0; i < 4; ++i) hreg[i] = h0[(b0+i)*1024 + j];

  unsigned short xs[12], xn[12];
  #pragma unroll
  for (int i = 0; i < 4; ++i) {
    const unsigned short* xp = (const unsigned short*)X + ((size_t)(b0+i))*3072 + j;
    xs[i] = xp[0]; xs[4+i] = xp[1024]; xs[8+i] = xp[2048];
  }

  const short* wlbase = Wl + lane*8;
  int* cnt = bar + bg*64;
  int tgt = 64;

  asm volatile("s_waitcnt vmcnt(0)" ::: "memory");

  for (int t = 0; t < 512; ++t) {
    const short* hbc = hb + (t&1)*65536;
    short* hbn = hb + ((t&1)^1)*65536;

    { // ---- phase 1: z, r ----
      const short* ap = hbc + (size_t)arow*1024 + kfo;
      s16x8 ah[32];
      cload8(ap,     ah[0], ah[1], ah[2], ah[3], ah[4], ah[5], ah[6], ah[7]);
      cload8(ap+256, ah[8], ah[9], ah[10],ah[11],ah[12],ah[13],ah[14],ah[15]);
      cload8(ap+512, ah[16],ah[17],ah[18],ah[19],ah[20],ah[21],ah[22],ah[23]);
      cload8(ap+768, ah[24],ah[25],ah[26],ah[27],ah[28],ah[29],ah[30],ah[31]);
      f32x4 acz = {0.f,0.f,0.f,0.f}, acr = {0.f,0.f,0.f,0.f};
      WAITV(24)
      #pragma unroll
      for (int n = 0; n < 8; ++n) {
        s16x8 vz = *(const s16x8*)(wlbase + n*512);
        s16x8 vr = *(const s16x8*)(wlbase + 16384 + n*512);
        acz = MFMA(ah[n], vz, acz);
        acr = MFMA(ah[n], vr, acr);
      }
      WAITV(16)
      #pragma unroll
      for (int n = 8; n < 16; ++n) {
        s16x8 vz = *(const s16x8*)(wlbase + n*512);
        s16x8 vr = *(const s16x8*)(wlbase + 16384 + n*512);
        acz = MFMA(ah[n], vz, acz);
        acr = MFMA(ah[n], vr, acr);
      }
      WAITV(8)
      #pragma unroll
      for (int n = 16; n < 24; ++n) {
        s16x8 vz = *(const s16x8*)(wlbase + n*512);
        s16x8 vr = *(const s16x8*)(wlbase + 16384 + n*512);
        acz = MFMA(ah[n], vz, acz);
        acr = MFMA(ah[n], vr, acr);
      }
      WAITV(0)
      #pragma unroll
      for (int n = 24; n < 32; ++n) {
        s16x8 vz = *(const s16x8*)(wlbase + n*512);
        s16x8 vr = *(const s16x8*)(wlbase + 16384 + n*512);
        acz = MFMA(ah[n], vz, acz);
        acr = MFMA(ah[n], vr, acr);
      }
      #pragma unroll
      for (int i = 0; i < 4; ++i) {
        zreg[i] = sigm(bf2f(xs[i]) + acz[i] + bz);
        float r = sigm(bf2f(xs[4+i]) + acr[i] + br);
        __hip_atomic_store(rh + (b0+i)*1024 + j, f2bf(r * hreg[i]),
                           __ATOMIC_RELAXED, __HIP_MEMORY_SCOPE_AGENT);
      }
    }
    // barrier: drain data stores, fire-and-forget arrival, broadcast poll
    asm volatile("s_waitcnt vmcnt(0)" ::: "memory");
    if (lane == 0)
      __hip_atomic_fetch_add(cnt, 1, __ATOMIC_RELAXED, __HIP_MEMORY_SCOPE_AGENT);
    {
      int v;
      do { v = __hip_atomic_load(cnt, __ATOMIC_RELAXED, __HIP_MEMORY_SCOPE_AGENT); }
      while (v < tgt);
      tgt += 64;
    }

    { // ---- phase 2: h_hat, combine ----
      const short* ap = rh + (size_t)arow*1024 + kfo;
      s16x8 ah[32];
      cload8(ap,     ah[0], ah[1], ah[2], ah[3], ah[4], ah[5], ah[6], ah[7]);
      cload8(ap+256, ah[8], ah[9], ah[10],ah[11],ah[12],ah[13],ah[14],ah[15]);
      cload8(ap+512, ah[16],ah[17],ah[18],ah[19],ah[20],ah[21],ah[22],ah[23]);
      cload8(ap+768, ah[24],ah[25],ah[26],ah[27],ah[28],ah[29],ah[30],ah[31]);
      f32x4 ach = {0.f,0.f,0.f,0.f};
      WAITV(24)
      #pragma unroll
      for (int n = 0; n < 8; ++n)
        ach = MFMA(ah[n], *(const s16x8*)(wlbase + 32768 + n*512), ach);
      WAITV(16)
      #pragma unroll
      for (int n = 8; n < 16; ++n)
        ach = MFMA(ah[n], *(const s16x8*)(wlbase + 32768 + n*512), ach);
      WAITV(8)
      #pragma unroll
      for (int n = 16; n < 24; ++n)
        ach = MFMA(ah[n], *(const s16x8*)(wlbase + 32768 + n*512), ach);
      WAITV(0)
      #pragma unroll
      for (int n = 24; n < 32; ++n)
        ach = MFMA(ah[n], *(const s16x8*)(wlbase + 32768 + n*512), ach);
      float hnv[4];
      #pragma unroll
      for (int i = 0; i < 4; ++i) {
        float s  = bf2f(xs[8+i]) + ach[i] + bh;
        float hh = s * sigm(s);
        float hn = (1.0f - zreg[i])*hreg[i] + zreg[i]*hh;
        hnv[i] = hn; hreg[i] = hn;
        __hip_atomic_store(hbn + (b0+i)*1024 + j, f2bf(hn),
                           __ATOMIC_RELAXED, __HIP_MEMORY_SCOPE_AGENT);
      }
      // barrier: drain h stores, arrive
      asm volatile("s_waitcnt vmcnt(0)" ::: "memory");
      if (lane == 0)
        __hip_atomic_fetch_add(cnt, 1, __ATOMIC_RELAXED, __HIP_MEMORY_SCOPE_AGENT);
      // off-critical-path work in the poll shadow: y stores, X prefetch, hlast
      #pragma unroll
      for (int i = 0; i < 4; ++i)
        __builtin_nontemporal_store(hnv[i], y + ((size_t)(b0+i)*512 + t)*1024 + j);
      int tn = (t+1) & 511;
      #pragma unroll
      for (int i = 0; i < 4; ++i) {
        const unsigned short* xp = (const unsigned short*)X + ((size_t)tn*64 + (b0+i))*3072 + j;
        xn[i] = xp[0]; xn[4+i] = xp[1024]; xn[8+i] = xp[2048];
      }
      if (t == 511) {
        #pragma unroll
        for (int i = 0; i < 4; ++i) hlast[(b0+i)*1024 + j] = hreg[i];
      }
      {
        int v;
        do { v = __hip_atomic_load(cnt, __ATOMIC_RELAXED, __HIP_MEMORY_SCOPE_AGENT); }
        while (v < tgt);
        tgt += 64;
      }
    }

    #pragma unroll
    for (int q = 0; q < 12; ++q) xs[q] = xn[q];
  }
}

extern "C" void kernel_launch(void* const* d_in, const int* in_sizes, int n_in,
                              void* d_out, int out_size, void* d_ws, size_t ws_size,
                              hipStream_t stream) {
  const float* x   = (const float*)d_in[0];
  const float* h0  = (const float*)d_in[1];
  const float* Wfz = (const float*)d_in[2];
  const float* bfz = (const float*)d_in[3];
  const float* Wfr = (const float*)d_in[4];
  const float* bfr = (const float*)d_in[5];
  const float* Wfh = (const float*)d_in[6];
  const float* bfh = (const float*)d_in[7];
  const float* Wuz = (const float*)d_in[8];
  const float* buz = (const float*)d_in[9];
  const float* Wur = (const float*)d_in[10];
  const float* bur = (const float*)d_in[11];
  const float* Wuh = (const float*)d_in[12];
  const float* buh = (const float*)d_in[13];

  char* ws = (char*)d_ws;
  short* Xb  = (short*)(ws);                  // 201326592 B  [512][64][3072] bf16
  short* xb  = (short*)(ws + 201326592);      //  67108864 B
  short* Wf  = (short*)(ws + 268435456);      //   6291456 B
  short* Wzr = (short*)(ws + 274726912);      //   4194304 B
  short* Wh  = (short*)(ws + 278921216);      //   2097152 B
  short* hb  = (short*)(ws + 281018368);      //    262144 B
  short* rh  = (short*)(ws + 281280512);      //    131072 B
  int*   bar = (int*)(ws + 281411584);        //    1024 B counters[4 domains]

  float* y = (float*)d_out;
  float* hlast = y + 33554432;

  hipMemsetAsync(bar, 0, 1024, stream);
  prep<<<2048, 256, 0, stream>>>(x, Wfz, Wfr, Wfh, Wuz, Wur, Wuh, h0, xb, Wf, Wzr, Wh, hb);
  gemm_x<<<6144, 256, 0, stream>>>(xb, Wf, bfz, bfr, bfh, Xb);
  recur<<<256, 64, 0, stream>>>(Xb, Wzr, Wh, h0, buz, bur, buh, hb, rh, y, hlast, bar);
}